// Round 3
// baseline (672.909 us; speedup 1.0000x reference)
//
#include <hip/hip_runtime.h>
#include <hip/hip_bf16.h>

#define N_ 8192
#define F_ 256
#define H_ 128
#define L_ 32

typedef __attribute__((ext_vector_type(8))) short bf16x8;
typedef __attribute__((ext_vector_type(4))) float f32x4;
typedef __attribute__((ext_vector_type(4))) short bf16x4;

// RNE float -> bf16 (finite inputs only)
__device__ __forceinline__ unsigned f2bf_u(float x) {
    unsigned u = __builtin_bit_cast(unsigned, x);
    return (u + 0x7fffu + ((u >> 16) & 1u)) >> 16;
}
__device__ __forceinline__ short f2bf(float x) { return (short)f2bf_u(x); }

__device__ __forceinline__ bf16x8 cvt8(float4 a, float4 b) {
    bf16x8 v;
    v[0] = f2bf(a.x); v[1] = f2bf(a.y); v[2] = f2bf(a.z); v[3] = f2bf(a.w);
    v[4] = f2bf(b.x); v[5] = f2bf(b.y); v[6] = f2bf(b.z); v[7] = f2bf(b.w);
    return v;
}

// ---------------------------------------------------------------------------
// k0: Ab = bf16(A), pure stream. 256 MB read + 128 MB write.
// ---------------------------------------------------------------------------
__global__ __launch_bounds__(256) void k0_cvt(const float* __restrict__ A,
                                              short* __restrict__ Ab) {
    size_t g = ((size_t)blockIdx.x * 256 + threadIdx.x) * 8;
    float4 a = *(const float4*)(A + g);
    float4 b = *(const float4*)(A + g + 4);
    *(bf16x8*)(Ab + g) = cvt8(a, b);
}

// ---------------------------------------------------------------------------
// k1: XW1T[n][i] = (X @ W1)[i][n], bf16.  64 rows/block, 4 waves x 16 rows.
// ---------------------------------------------------------------------------
__global__ __launch_bounds__(256) void k1_xw1(const float* __restrict__ X,
                                              const float* __restrict__ W1,
                                              short* __restrict__ XW1T) {
    __shared__ short w1t[H_ * (F_ + 8)];
    const int tid = threadIdx.x;
    for (int idx = tid; idx < F_ * H_; idx += 256) {
        int k = idx >> 7, n = idx & 127;
        w1t[n * (F_ + 8) + k] = f2bf(W1[idx]);
    }
    __syncthreads();
    const int wv = tid >> 6, l = tid & 63;
    const int lm = l & 15, q = l >> 4;
    const int i0 = blockIdx.x * 64 + wv * 16;
    const float* xrow = X + (size_t)(i0 + lm) * F_;
    f32x4 acc[8];
#pragma unroll
    for (int j = 0; j < 8; ++j) acc[j] = (f32x4){0.f, 0.f, 0.f, 0.f};
#pragma unroll
    for (int k0 = 0; k0 < F_; k0 += 32) {
        float4 a0 = *(const float4*)(xrow + k0 + q * 8);
        float4 a1 = *(const float4*)(xrow + k0 + q * 8 + 4);
        bf16x8 af = cvt8(a0, a1);
#pragma unroll
        for (int j = 0; j < 8; ++j) {
            bf16x8 bf = *(const bf16x8*)&w1t[(j * 16 + lm) * (F_ + 8) + k0 + q * 8];
            acc[j] = __builtin_amdgcn_mfma_f32_16x16x32_bf16(af, bf, acc[j], 0, 0, 0);
        }
    }
#pragma unroll
    for (int j = 0; j < 8; ++j) {
        bf16x4 o;
        o[0] = f2bf(acc[j][0]); o[1] = f2bf(acc[j][1]);
        o[2] = f2bf(acc[j][2]); o[3] = f2bf(acc[j][3]);
        *(bf16x4*)(XW1T + (size_t)(j * 16 + lm) * N_ + i0 + q * 4) = o;
    }
}

// ---------------------------------------------------------------------------
// k2: ZPT[j][i] = (relu(Ab @ XW1) @ W2)[i][j], bf16.
// 16 rows/block, 4 waves = 4 K-quarters. NO LDS in hot loop, no barriers:
// direct global fragment loads (16-row x 64B segments), register pipeline D=2.
// ---------------------------------------------------------------------------
__global__ __launch_bounds__(256) void k2_h_zp(const short* __restrict__ Ab,
                                               const short* __restrict__ XW1T,
                                               const float* __restrict__ W2,
                                               short* __restrict__ ZPT) {
    __shared__ float lacc[4][16][132];   // 33.8 KB
    __shared__ short hl[16][136];        // 4.3 KB
    __shared__ short w2t[32][136];       // 8.7 KB
    const int tid = threadIdx.x;
    for (int idx = tid; idx < H_ * L_; idx += 256) {
        int k = idx >> 5, j = idx & 31;
        w2t[j][k] = f2bf(W2[idx]);
    }
    const int wv = tid >> 6, l = tid & 63, lm = l & 15, q = l >> 4;
    const int i0 = blockIdx.x * 16;
    const int kbeg = wv * (N_ / 4);
    const short* Arow = Ab + (size_t)(i0 + lm) * N_ + kbeg + q * 8;
    const short* Bp[8];
#pragma unroll
    for (int jt = 0; jt < 8; ++jt)
        Bp[jt] = XW1T + (size_t)(jt * 16 + lm) * N_ + kbeg + q * 8;

    bf16x8 pa[2], pb[2][8];
#pragma unroll
    for (int t = 0; t < 2; ++t) {
        pa[t] = *(const bf16x8*)(Arow + t * 32);
#pragma unroll
        for (int jt = 0; jt < 8; ++jt) pb[t][jt] = *(const bf16x8*)(Bp[jt] + t * 32);
    }
    f32x4 acc[8];
#pragma unroll
    for (int j = 0; j < 8; ++j) acc[j] = (f32x4){0.f, 0.f, 0.f, 0.f};

    const int NS = (N_ / 4) / 32;   // 64
#pragma unroll 2
    for (int s = 0; s < NS; ++s) {
        const int p = s & 1;
        bf16x8 af = pa[p];
#pragma unroll
        for (int jt = 0; jt < 8; ++jt)
            acc[jt] = __builtin_amdgcn_mfma_f32_16x16x32_bf16(af, pb[p][jt], acc[jt], 0, 0, 0);
        if (s + 2 < NS) {
            pa[p] = *(const bf16x8*)(Arow + (s + 2) * 32);
#pragma unroll
            for (int jt = 0; jt < 8; ++jt)
                pb[p][jt] = *(const bf16x8*)(Bp[jt] + (s + 2) * 32);
        }
    }
    // K-quarter reduce + relu + @W2 epilogue
#pragma unroll
    for (int jt = 0; jt < 8; ++jt)
#pragma unroll
        for (int r = 0; r < 4; ++r)
            lacc[wv][q * 4 + r][jt * 16 + lm] = acc[jt][r];
    __syncthreads();
    for (int e = tid; e < 16 * H_; e += 256) {
        int rr = e >> 7, c = e & 127;
        float v = (lacc[0][rr][c] + lacc[1][rr][c]) + (lacc[2][rr][c] + lacc[3][rr][c]);
        hl[rr][c] = f2bf(v > 0.f ? v : 0.f);
    }
    __syncthreads();
    if (wv < 2) {   // two 16x16 output tiles of h(16x128) @ W2(128x32)
        f32x4 a2 = (f32x4){0.f, 0.f, 0.f, 0.f};
#pragma unroll
        for (int k0 = 0; k0 < H_; k0 += 32) {
            bf16x8 af2 = *(const bf16x8*)&hl[lm][k0 + q * 8];
            bf16x8 bf2 = *(const bf16x8*)&w2t[wv * 16 + lm][k0 + q * 8];
            a2 = __builtin_amdgcn_mfma_f32_16x16x32_bf16(af2, bf2, a2, 0, 0, 0);
        }
        bf16x4 o;
        o[0] = f2bf(a2[0]); o[1] = f2bf(a2[1]); o[2] = f2bf(a2[2]); o[3] = f2bf(a2[3]);
        *(bf16x4*)(ZPT + (size_t)(wv * 16 + lm) * N_ + i0 + q * 4) = o;
    }
}

// ---------------------------------------------------------------------------
// k3: Z[i][j] = (Ab @ ZP)[i][j], bf16 row-major. Same decoupled skeleton.
// ---------------------------------------------------------------------------
__global__ __launch_bounds__(256) void k3_z(const short* __restrict__ Ab,
                                            const short* __restrict__ ZPT,
                                            short* __restrict__ Z) {
    __shared__ float lacc[4][16][36];   // 9.2 KB
    const int tid = threadIdx.x;
    const int wv = tid >> 6, l = tid & 63, lm = l & 15, q = l >> 4;
    const int i0 = blockIdx.x * 16;
    const int kbeg = wv * (N_ / 4);
    const short* Arow = Ab + (size_t)(i0 + lm) * N_ + kbeg + q * 8;
    const short* Bp0 = ZPT + (size_t)lm * N_ + kbeg + q * 8;
    const short* Bp1 = Bp0 + (size_t)16 * N_;

    bf16x8 pa[2], pb0[2], pb1[2];
#pragma unroll
    for (int t = 0; t < 2; ++t) {
        pa[t]  = *(const bf16x8*)(Arow + t * 32);
        pb0[t] = *(const bf16x8*)(Bp0 + t * 32);
        pb1[t] = *(const bf16x8*)(Bp1 + t * 32);
    }
    f32x4 acc0 = (f32x4){0.f, 0.f, 0.f, 0.f};
    f32x4 acc1 = (f32x4){0.f, 0.f, 0.f, 0.f};
    const int NS = (N_ / 4) / 32;   // 64
#pragma unroll 2
    for (int s = 0; s < NS; ++s) {
        const int p = s & 1;
        acc0 = __builtin_amdgcn_mfma_f32_16x16x32_bf16(pa[p], pb0[p], acc0, 0, 0, 0);
        acc1 = __builtin_amdgcn_mfma_f32_16x16x32_bf16(pa[p], pb1[p], acc1, 0, 0, 0);
        if (s + 2 < NS) {
            pa[p]  = *(const bf16x8*)(Arow + (s + 2) * 32);
            pb0[p] = *(const bf16x8*)(Bp0 + (s + 2) * 32);
            pb1[p] = *(const bf16x8*)(Bp1 + (s + 2) * 32);
        }
    }
#pragma unroll
    for (int r = 0; r < 4; ++r) {
        lacc[wv][q * 4 + r][lm]      = acc0[r];
        lacc[wv][q * 4 + r][16 + lm] = acc1[r];
    }
    __syncthreads();
    {   // 512 outputs, 256 threads -> one packed u32 each
        int e = tid * 2;
        int rr = e >> 5, c = e & 31;
        float v0 = (lacc[0][rr][c] + lacc[1][rr][c]) + (lacc[2][rr][c] + lacc[3][rr][c]);
        float v1 = (lacc[0][rr][c + 1] + lacc[1][rr][c + 1]) + (lacc[2][rr][c + 1] + lacc[3][rr][c + 1]);
        unsigned pk = f2bf_u(v0) | (f2bf_u(v1) << 16);
        *(unsigned*)(Z + (size_t)(i0 + rr) * L_ + c) = pk;
    }
}

// ---------------------------------------------------------------------------
// k4: out = sigmoid(Z @ Z^T). 128x128/block; sigmoid -> LDS -> coalesced
// float4 stores.
// ---------------------------------------------------------------------------
__global__ __launch_bounds__(256) void k4_dec(const short* __restrict__ Z,
                                              float* __restrict__ out) {
    __shared__ float os[128][132];   // 67.6 KB -> 2 blocks/CU
    const int tid = threadIdx.x;
    const int wv = tid >> 6, l = tid & 63;
    const int lm = l & 15, q = l >> 4;
    const int bj = blockIdx.x & 63, bi = blockIdx.x >> 6;
    const int i0 = bi * 128, j0 = bj * 128;
    bf16x8 af[2];
#pragma unroll
    for (int t = 0; t < 2; ++t)
        af[t] = *(const bf16x8*)(Z + (size_t)(i0 + wv * 32 + t * 16 + lm) * L_ + q * 8);
#pragma unroll
    for (int tj = 0; tj < 8; ++tj) {
        bf16x8 bfv = *(const bf16x8*)(Z + (size_t)(j0 + tj * 16 + lm) * L_ + q * 8);
#pragma unroll
        for (int t = 0; t < 2; ++t) {
            f32x4 c = __builtin_amdgcn_mfma_f32_16x16x32_bf16(
                af[t], bfv, (f32x4){0.f, 0.f, 0.f, 0.f}, 0, 0, 0);
#pragma unroll
            for (int r = 0; r < 4; ++r) {
                float e = __expf(-c[r]);
                os[wv * 32 + t * 16 + q * 4 + r][tj * 16 + lm] = __fdividef(1.f, 1.f + e);
            }
        }
    }
    __syncthreads();
    for (int idx = tid; idx < 128 * 32; idx += 256) {
        int row = idx >> 5, c4 = idx & 31;
        *(float4*)(out + (size_t)(i0 + row) * N_ + j0 + c4 * 4) = *(const float4*)&os[row][c4 * 4];
    }
}

extern "C" void kernel_launch(void* const* d_in, const int* in_sizes, int n_in,
                              void* d_out, int out_size, void* d_ws, size_t ws_size,
                              hipStream_t stream) {
    const float* X  = (const float*)d_in[0];
    const float* A  = (const float*)d_in[1];
    const float* W1 = (const float*)d_in[2];
    const float* W2 = (const float*)d_in[3];
    float* out = (float*)d_out;

    short* XW1T = (short*)d_ws;            // [H][N] bf16, 2 MB
    short* ZPT  = XW1T + (size_t)H_ * N_;  // [L][N] bf16, 512 KB
    short* Z    = ZPT + (size_t)L_ * N_;   // [N][L] bf16, 512 KB
    short* Ab   = Z + (size_t)N_ * L_;     // [N][N] bf16, 128 MB

    k1_xw1<<<N_ / 64, 256, 0, stream>>>(X, W1, XW1T);
    k0_cvt<<<(N_ * N_) / (256 * 8), 256, 0, stream>>>(A, Ab);
    k2_h_zp<<<N_ / 16, 256, 0, stream>>>(Ab, XW1T, W2, ZPT);
    k3_z<<<N_ / 16, 256, 0, stream>>>(Ab, ZPT, Z);
    k4_dec<<<(N_ / 128) * (N_ / 128), 256, 0, stream>>>(Z, out);
}

// Round 4
// 561.034 us; speedup vs baseline: 1.1994x; 1.1994x over previous
//
#include <hip/hip_runtime.h>
#include <hip/hip_bf16.h>

#define N_ 8192
#define F_ 256
#define H_ 128
#define L_ 32
#define TK 64
#define KQN 4
#define KQL (N_ / KQN)   // 2048

typedef __attribute__((ext_vector_type(8))) short bf16x8;
typedef __attribute__((ext_vector_type(4))) float f32x4;
typedef __attribute__((ext_vector_type(4))) short bf16x4;

// RNE float -> bf16 (finite inputs only)
__device__ __forceinline__ unsigned f2bf_u(float x) {
    unsigned u = __builtin_bit_cast(unsigned, x);
    return (u + 0x7fffu + ((u >> 16) & 1u)) >> 16;
}
__device__ __forceinline__ short f2bf(float x) { return (short)f2bf_u(x); }

__device__ __forceinline__ bf16x4 cvt4(float4 a) {
    bf16x4 v;
    v[0] = f2bf(a.x); v[1] = f2bf(a.y); v[2] = f2bf(a.z); v[3] = f2bf(a.w);
    return v;
}
__device__ __forceinline__ bf16x8 cvt8(float4 a, float4 b) {
    bf16x8 v;
    v[0] = f2bf(a.x); v[1] = f2bf(a.y); v[2] = f2bf(a.z); v[3] = f2bf(a.w);
    v[4] = f2bf(b.x); v[5] = f2bf(b.y); v[6] = f2bf(b.z); v[7] = f2bf(b.w);
    return v;
}

// ---------------------------------------------------------------------------
// k1: XW1T[n][i] = (X @ W1)[i][n], bf16.  64 rows/block, 4 waves x 16 rows.
// ---------------------------------------------------------------------------
__global__ __launch_bounds__(256) void k1_xw1(const float* __restrict__ X,
                                              const float* __restrict__ W1,
                                              short* __restrict__ XW1T) {
    __shared__ short w1t[H_ * (F_ + 8)];
    const int tid = threadIdx.x;
    for (int idx = tid; idx < F_ * H_; idx += 256) {
        int k = idx >> 7, n = idx & 127;
        w1t[n * (F_ + 8) + k] = f2bf(W1[idx]);
    }
    __syncthreads();
    const int wv = tid >> 6, l = tid & 63;
    const int lm = l & 15, q = l >> 4;
    const int i0 = blockIdx.x * 64 + wv * 16;
    const float* xrow = X + (size_t)(i0 + lm) * F_;
    f32x4 acc[8];
#pragma unroll
    for (int j = 0; j < 8; ++j) acc[j] = (f32x4){0.f, 0.f, 0.f, 0.f};
#pragma unroll
    for (int k0 = 0; k0 < F_; k0 += 32) {
        float4 a0 = *(const float4*)(xrow + k0 + q * 8);
        float4 a1 = *(const float4*)(xrow + k0 + q * 8 + 4);
        bf16x8 af = cvt8(a0, a1);
#pragma unroll
        for (int j = 0; j < 8; ++j) {
            bf16x8 bf = *(const bf16x8*)&w1t[(j * 16 + lm) * (F_ + 8) + k0 + q * 8];
            acc[j] = __builtin_amdgcn_mfma_f32_16x16x32_bf16(af, bf, acc[j], 0, 0, 0);
        }
    }
#pragma unroll
    for (int j = 0; j < 8; ++j) {
        bf16x4 o;
        o[0] = f2bf(acc[j][0]); o[1] = f2bf(acc[j][1]);
        o[2] = f2bf(acc[j][2]); o[3] = f2bf(acc[j][3]);
        *(bf16x4*)(XW1T + (size_t)(j * 16 + lm) * N_ + i0 + q * 4) = o;
    }
}

// ---------------------------------------------------------------------------
// k2a: P4[kq][i][n] += A[i, kq-slice] @ XW1[kq-slice, n]  (fp32 partials)
// 512 blocks = 128 row-tiles(64) x 4 K-quarters; 8 waves; dbuf LDS staging.
// ---------------------------------------------------------------------------
__global__ __launch_bounds__(512) void k2a(const float* __restrict__ A,
                                           const short* __restrict__ XW1T,
                                           float* __restrict__ P4) {
    __shared__ short As[2][64][72];    // 18.4 KB
    __shared__ short Bs[2][128][72];   // 36.9 KB
    const int tid = threadIdx.x;
    const int bi = blockIdx.x >> 2, kq = blockIdx.x & 3;
    const int i0 = bi * 64, kbase = kq * KQL;
    // staging coords: A 64x64 fp32, thread does rows ar, ar+32 (float4 each)
    const int ar = tid >> 4, ac = (tid & 15) * 4;
    // B 128x64 bf16, thread does rows br, br+64 (bf16x8 each)
    const int br = tid >> 3, bc = (tid & 7) * 8;
    const float* Ap = A + (size_t)(i0 + ar) * N_ + kbase + ac;
    const short* Bp = XW1T + (size_t)br * N_ + kbase + bc;

    const int wv = tid >> 6, l = tid & 63, lm = l & 15, q = l >> 4;
    const int rg = wv & 3, ch = wv >> 2;   // 4 row-groups x 2 col-halves

    float4 pa0, pa1; bf16x8 pb0, pb1;
#define LOADG(s) do { size_t o = (size_t)(s) * TK; \
        pa0 = *(const float4*)(Ap + o); \
        pa1 = *(const float4*)(Ap + o + (size_t)32 * N_); \
        pb0 = *(const bf16x8*)(Bp + o); \
        pb1 = *(const bf16x8*)(Bp + o + (size_t)64 * N_); } while (0)
#define STORES(b) do { \
        *(bf16x4*)&As[b][ar][ac] = cvt4(pa0); \
        *(bf16x4*)&As[b][ar + 32][ac] = cvt4(pa1); \
        *(bf16x8*)&Bs[b][br][bc] = pb0; \
        *(bf16x8*)&Bs[b][br + 64][bc] = pb1; } while (0)

    LOADG(0); STORES(0); LOADG(1);
    __syncthreads();

    f32x4 acc[4];
#pragma unroll
    for (int j = 0; j < 4; ++j) acc[j] = (f32x4){0.f, 0.f, 0.f, 0.f};
    const int NS = KQL / TK;   // 32
#pragma unroll 2
    for (int s = 0; s < NS; ++s) {
        const int b = s & 1;
#pragma unroll
        for (int kh = 0; kh < 2; ++kh) {
            bf16x8 af = *(const bf16x8*)&As[b][rg * 16 + lm][kh * 32 + q * 8];
#pragma unroll
            for (int jt = 0; jt < 4; ++jt) {
                bf16x8 bfv = *(const bf16x8*)&Bs[b][ch * 64 + jt * 16 + lm][kh * 32 + q * 8];
                acc[jt] = __builtin_amdgcn_mfma_f32_16x16x32_bf16(af, bfv, acc[jt], 0, 0, 0);
            }
        }
        if (s + 1 < NS) {
            STORES((s + 1) & 1);
            if (s + 2 < NS) LOADG(s + 2);
        }
        __syncthreads();
    }
#undef LOADG
#undef STORES
    // store partials: row = i0+rg*16+q*4+r, col = ch*64+jt*16+lm
    float* Pb = P4 + ((size_t)kq * N_ + i0 + rg * 16 + q * 4) * H_ + ch * 64 + lm;
#pragma unroll
    for (int jt = 0; jt < 4; ++jt)
#pragma unroll
        for (int r = 0; r < 4; ++r)
            Pb[(size_t)r * H_ + jt * 16] = acc[jt][r];
}

// ---------------------------------------------------------------------------
// k2b: ZPT[j][i] = ((relu(sum_kq P4)) @ W2)[i][j], bf16. 32 rows/block.
// ---------------------------------------------------------------------------
__global__ __launch_bounds__(256) void k2b(const float* __restrict__ P4,
                                           const float* __restrict__ W2,
                                           short* __restrict__ ZPT) {
    __shared__ short hl[32][136];
    __shared__ short w2t[32][136];
    const int tid = threadIdx.x;
    for (int idx = tid; idx < H_ * L_; idx += 256) {
        int k = idx >> 5, j = idx & 31;
        w2t[j][k] = f2bf(W2[idx]);
    }
    const int i0 = blockIdx.x * 32;
    const int r = tid >> 3, c16 = (tid & 7) * 16;
    float4 v[4];
#pragma unroll
    for (int cc = 0; cc < 4; ++cc) v[cc] = (float4){0.f, 0.f, 0.f, 0.f};
#pragma unroll
    for (int kq = 0; kq < 4; ++kq) {
        const float* p = P4 + ((size_t)kq * N_ + i0 + r) * H_ + c16;
#pragma unroll
        for (int cc = 0; cc < 4; ++cc) {
            float4 t = *(const float4*)(p + cc * 4);
            v[cc].x += t.x; v[cc].y += t.y; v[cc].z += t.z; v[cc].w += t.w;
        }
    }
#pragma unroll
    for (int cc = 0; cc < 4; ++cc) {
        v[cc].x = v[cc].x > 0.f ? v[cc].x : 0.f;
        v[cc].y = v[cc].y > 0.f ? v[cc].y : 0.f;
        v[cc].z = v[cc].z > 0.f ? v[cc].z : 0.f;
        v[cc].w = v[cc].w > 0.f ? v[cc].w : 0.f;
    }
    *(bf16x8*)&hl[r][c16] = cvt8(v[0], v[1]);
    *(bf16x8*)&hl[r][c16 + 8] = cvt8(v[2], v[3]);
    __syncthreads();
    const int wv = tid >> 6, l = tid & 63, lm = l & 15, q = l >> 4;
    const int ti = wv & 1, tj = wv >> 1;
    f32x4 a2 = (f32x4){0.f, 0.f, 0.f, 0.f};
#pragma unroll
    for (int k0 = 0; k0 < H_; k0 += 32) {
        bf16x8 af = *(const bf16x8*)&hl[ti * 16 + lm][k0 + q * 8];
        bf16x8 bf = *(const bf16x8*)&w2t[tj * 16 + lm][k0 + q * 8];
        a2 = __builtin_amdgcn_mfma_f32_16x16x32_bf16(af, bf, a2, 0, 0, 0);
    }
    bf16x4 o;
    o[0] = f2bf(a2[0]); o[1] = f2bf(a2[1]); o[2] = f2bf(a2[2]); o[3] = f2bf(a2[3]);
    *(bf16x4*)(ZPT + (size_t)(tj * 16 + lm) * N_ + i0 + ti * 16 + q * 4) = o;
}

// ---------------------------------------------------------------------------
// k3a: Q4[kq][i][j] += A[i, kq-slice] @ ZP[kq-slice, j]  (fp32 partials)
// Same skeleton as k2a; B has 32 cols.
// ---------------------------------------------------------------------------
__global__ __launch_bounds__(512) void k3a(const float* __restrict__ A,
                                           const short* __restrict__ ZPT,
                                           float* __restrict__ Q4) {
    __shared__ short As[2][64][72];   // 18.4 KB
    __shared__ short Bs[2][32][72];   // 9.2 KB
    const int tid = threadIdx.x;
    const int bi = blockIdx.x >> 2, kq = blockIdx.x & 3;
    const int i0 = bi * 64, kbase = kq * KQL;
    const int ar = tid >> 4, ac = (tid & 15) * 4;
    const int br = tid >> 4, bc = (tid & 15) * 4;   // B: 32 rows x 64 bf16, bf16x4 each
    const float* Ap = A + (size_t)(i0 + ar) * N_ + kbase + ac;
    const short* Bp = ZPT + (size_t)br * N_ + kbase + bc;

    const int wv = tid >> 6, l = tid & 63, lm = l & 15, q = l >> 4;
    const int rg = wv & 3, ch = wv >> 2;   // 4 row-groups x 2 col-halves(16)

    float4 pa0, pa1; bf16x4 pb0;
#define LOADG(s) do { size_t o = (size_t)(s) * TK; \
        pa0 = *(const float4*)(Ap + o); \
        pa1 = *(const float4*)(Ap + o + (size_t)32 * N_); \
        pb0 = *(const bf16x4*)(Bp + o); } while (0)
#define STORES(b) do { \
        *(bf16x4*)&As[b][ar][ac] = cvt4(pa0); \
        *(bf16x4*)&As[b][ar + 32][ac] = cvt4(pa1); \
        *(bf16x4*)&Bs[b][br][bc] = pb0; } while (0)

    LOADG(0); STORES(0); LOADG(1);
    __syncthreads();

    f32x4 acc = (f32x4){0.f, 0.f, 0.f, 0.f};
    const int NS = KQL / TK;   // 32
#pragma unroll 2
    for (int s = 0; s < NS; ++s) {
        const int b = s & 1;
#pragma unroll
        for (int kh = 0; kh < 2; ++kh) {
            bf16x8 af = *(const bf16x8*)&As[b][rg * 16 + lm][kh * 32 + q * 8];
            bf16x8 bfv = *(const bf16x8*)&Bs[b][ch * 16 + lm][kh * 32 + q * 8];
            acc = __builtin_amdgcn_mfma_f32_16x16x32_bf16(af, bfv, acc, 0, 0, 0);
        }
        if (s + 1 < NS) {
            STORES((s + 1) & 1);
            if (s + 2 < NS) LOADG(s + 2);
        }
        __syncthreads();
    }
#undef LOADG
#undef STORES
    float* Qb = Q4 + ((size_t)kq * N_ + i0 + rg * 16 + q * 4) * L_ + ch * 16 + lm;
#pragma unroll
    for (int r = 0; r < 4; ++r)
        Qb[(size_t)r * L_] = acc[r];
}

// ---------------------------------------------------------------------------
// k3b: Z = bf16(sum_kq Q4), flat elementwise.
// ---------------------------------------------------------------------------
__global__ __launch_bounds__(256) void k3b(const float* __restrict__ Q4,
                                           short* __restrict__ Z) {
    size_t g = ((size_t)blockIdx.x * 256 + threadIdx.x) * 8;
    float4 s0 = (float4){0.f, 0.f, 0.f, 0.f}, s1 = s0;
#pragma unroll
    for (int kq = 0; kq < 4; ++kq) {
        const float* p = Q4 + (size_t)kq * N_ * L_ + g;
        float4 a = *(const float4*)(p);
        float4 b = *(const float4*)(p + 4);
        s0.x += a.x; s0.y += a.y; s0.z += a.z; s0.w += a.w;
        s1.x += b.x; s1.y += b.y; s1.z += b.z; s1.w += b.w;
    }
    *(bf16x8*)(Z + g) = cvt8(s0, s1);
}

// ---------------------------------------------------------------------------
// k4: out = sigmoid(Z @ Z^T). 128x128/block; sigmoid -> LDS -> coalesced
// float4 stores.
// ---------------------------------------------------------------------------
__global__ __launch_bounds__(256) void k4_dec(const short* __restrict__ Z,
                                              float* __restrict__ out) {
    __shared__ float os[128][132];   // 67.6 KB
    const int tid = threadIdx.x;
    const int wv = tid >> 6, l = tid & 63;
    const int lm = l & 15, q = l >> 4;
    const int bj = blockIdx.x & 63, bi = blockIdx.x >> 6;
    const int i0 = bi * 128, j0 = bj * 128;
    bf16x8 af[2];
#pragma unroll
    for (int t = 0; t < 2; ++t)
        af[t] = *(const bf16x8*)(Z + (size_t)(i0 + wv * 32 + t * 16 + lm) * L_ + q * 8);
#pragma unroll
    for (int tj = 0; tj < 8; ++tj) {
        bf16x8 bfv = *(const bf16x8*)(Z + (size_t)(j0 + tj * 16 + lm) * L_ + q * 8);
#pragma unroll
        for (int t = 0; t < 2; ++t) {
            f32x4 c = __builtin_amdgcn_mfma_f32_16x16x32_bf16(
                af[t], bfv, (f32x4){0.f, 0.f, 0.f, 0.f}, 0, 0, 0);
#pragma unroll
            for (int r = 0; r < 4; ++r) {
                float e = __expf(-c[r]);
                os[wv * 32 + t * 16 + q * 4 + r][tj * 16 + lm] = __fdividef(1.f, 1.f + e);
            }
        }
    }
    __syncthreads();
    for (int idx = tid; idx < 128 * 32; idx += 256) {
        int row = idx >> 5, c4 = idx & 31;
        *(float4*)(out + (size_t)(i0 + row) * N_ + j0 + c4 * 4) = *(const float4*)&os[row][c4 * 4];
    }
}

extern "C" void kernel_launch(void* const* d_in, const int* in_sizes, int n_in,
                              void* d_out, int out_size, void* d_ws, size_t ws_size,
                              hipStream_t stream) {
    const float* X  = (const float*)d_in[0];
    const float* A  = (const float*)d_in[1];
    const float* W1 = (const float*)d_in[2];
    const float* W2 = (const float*)d_in[3];
    float* out = (float*)d_out;

    short* XW1T = (short*)d_ws;                    // [H][N] bf16, 2 MB
    short* ZPT  = XW1T + (size_t)H_ * N_;          // [L][N] bf16, 512 KB
    short* Z    = ZPT + (size_t)L_ * N_;           // [N][L] bf16, 512 KB
    float* P4   = (float*)(Z + (size_t)N_ * L_);   // [4][N][H] fp32, 16 MB
    float* Q4   = P4 + (size_t)4 * N_ * H_;        // [4][N][L] fp32, 4 MB

    k1_xw1<<<N_ / 64, 256, 0, stream>>>(X, W1, XW1T);
    k2a<<<(N_ / 64) * KQN, 512, 0, stream>>>(A, XW1T, P4);
    k2b<<<N_ / 32, 256, 0, stream>>>(P4, W2, ZPT);
    k3a<<<(N_ / 64) * KQN, 512, 0, stream>>>(A, ZPT, Q4);
    k3b<<<(N_ * L_) / (256 * 8), 256, 0, stream>>>(Q4, Z);
    k4_dec<<<(N_ / 128) * (N_ / 128), 256, 0, stream>>>(Z, out);
}